// Round 3
// baseline (81.106 us; speedup 1.0000x reference)
//
#include <hip/hip_runtime.h>
#include <hip/hip_bf16.h>

// B=128, C=32, K=128
// out[b,c,i,j] = s[b,c],  s[b,c] = sum_k (u[c,k]+b_row[c]) * (v[c,k]+b_col[c])
//   u[c,k] = sum_i w_row[c,i] * X[b,i,k]   (column dot -> xt row read)
//   v[c,k] = sum_j w_col[c,j] * X[b,k,j]   (row dot    -> xt column read)

constexpr int KDIM = 128;
constexpr int CDIM = 32;

typedef float f32x4 __attribute__((ext_vector_type(4)));

// XOR-swizzled word index into a [128][128] f32 LDS tile.
// 16B-chunk swizzle: chunk = (col>>2) ^ ((row>>2)&7). Conflict-free for:
//  - tile-transposed ds_write_b128 staging
//  - row-wise ds_read_b128 (u loop)
//  - column-wise ds_read_b32 (v loop)
__device__ __forceinline__ int swz_word(int row, int col) {
    return (row << 7) | ((((col >> 2) ^ ((row >> 2) & 7)) << 2) | (col & 3));
}

// grid = 256: blockIdx.x = b*2 + chalf ; block = 256 threads
__global__ __launch_bounds__(256) void compute_s_kernel(
    const float* __restrict__ x,
    const float* __restrict__ w_col, const float* __restrict__ b_col,
    const float* __restrict__ w_row, const float* __restrict__ b_row,
    float* __restrict__ s_out)
{
    __shared__ float xt[KDIM * KDIM];      // swizzled: xt[swz(k,i)] = X[i][k]  (64 KB)
    __shared__ float uv[2][16][KDIM];      // u and v results (16 KB)

    const int b   = blockIdx.x >> 1;
    const int ch  = blockIdx.x & 1;
    const int tid = threadIdx.x;

    // ---- stage X^T into swizzled LDS via 4x4 register tiles ----
    const float4* xsrc = reinterpret_cast<const float4*>(x + (size_t)b * KDIM * KDIM);
    const int tj  = tid & 31;    // column tile of X (row tile of xt)
    const int ti0 = tid >> 5;    // 0..7
    #pragma unroll
    for (int it = 0; it < 4; ++it) {
        const int ti = ti0 + 8 * it;                 // row tile of X, 0..31
        const float4 r0 = xsrc[(4 * ti + 0) * 32 + tj];   // coalesced
        const float4 r1 = xsrc[(4 * ti + 1) * 32 + tj];
        const float4 r2 = xsrc[(4 * ti + 2) * 32 + tj];
        const float4 r3 = xsrc[(4 * ti + 3) * 32 + tj];
        // xt row 4tj+t, cols 4ti..4ti+3  =  X[4ti..4ti+3][4tj+t]
        *reinterpret_cast<float4*>(&xt[swz_word(4 * tj + 0, 4 * ti)]) =
            make_float4(r0.x, r1.x, r2.x, r3.x);
        *reinterpret_cast<float4*>(&xt[swz_word(4 * tj + 1, 4 * ti)]) =
            make_float4(r0.y, r1.y, r2.y, r3.y);
        *reinterpret_cast<float4*>(&xt[swz_word(4 * tj + 2, 4 * ti)]) =
            make_float4(r0.z, r1.z, r2.z, r3.z);
        *reinterpret_cast<float4*>(&xt[swz_word(4 * tj + 3, 4 * ti)]) =
            make_float4(r0.w, r1.w, r2.w, r3.w);
    }
    __syncthreads();

    const int k   = tid & 127;
    const int sub = tid >> 7;    // wave-uniform: 0 -> u, 1 -> v

    float acc[16];
    #pragma unroll
    for (int c = 0; c < 16; ++c) acc[c] = 0.0f;

    if (sub == 0) {
        // u[c,k] = sum_i wr[c,i] * xt[k][i] — row read, ds_read_b128
        const float* wr = w_row + ch * 16 * KDIM;    // wave-uniform -> s_load
        #pragma unroll 4
        for (int iq = 0; iq < 32; ++iq) {
            const float4 xv = *reinterpret_cast<const float4*>(&xt[swz_word(k, iq << 2)]);
            #pragma unroll
            for (int c = 0; c < 16; ++c) {
                acc[c] = fmaf(wr[c * KDIM + 4 * iq + 0], xv.x, acc[c]);
                acc[c] = fmaf(wr[c * KDIM + 4 * iq + 1], xv.y, acc[c]);
                acc[c] = fmaf(wr[c * KDIM + 4 * iq + 2], xv.z, acc[c]);
                acc[c] = fmaf(wr[c * KDIM + 4 * iq + 3], xv.w, acc[c]);
            }
        }
    } else {
        // v[c,k] = sum_j wc[c,j] * xt[j][k] — column read, ds_read_b32 conflict-free
        const float* wc = w_col + ch * 16 * KDIM;    // wave-uniform -> s_load
        #pragma unroll 4
        for (int j = 0; j < KDIM; ++j) {
            const float xj = xt[swz_word(j, k)];
            #pragma unroll
            for (int c = 0; c < 16; ++c)
                acc[c] = fmaf(wc[c * KDIM + j], xj, acc[c]);
        }
    }
    #pragma unroll
    for (int c = 0; c < 16; ++c) uv[sub][c][k] = acc[c];
    __syncthreads();

    // ---- reduce over k: 16 groups of 16 lanes, group g owns c = ch*16 + g ----
    const int g    = tid >> 4;
    const int lane = tid & 15;
    const int cg   = ch * 16 + g;
    const float br = b_row[cg];
    const float bc = b_col[cg];

    float part = 0.0f;
    #pragma unroll
    for (int r = 0; r < 8; ++r) {
        const int kk = lane + 16 * r;
        part += (uv[0][g][kk] + br) * (uv[1][g][kk] + bc);
    }
    #pragma unroll
    for (int off = 8; off; off >>= 1)
        part += __shfl_xor(part, off, 16);

    if (lane == 0) s_out[b * CDIM + cg] = part;
}

// grid = 4096 (one block per (b,c) slab of 16384 floats), block = 256
__global__ __launch_bounds__(256) void bcast_kernel(
    const float* __restrict__ s, float* __restrict__ out)
{
    const int bc = blockIdx.x;
    const float val = s[bc];
    f32x4 v4 = {val, val, val, val};
    f32x4* o = reinterpret_cast<f32x4*>(out) + (size_t)bc * 4096;
    #pragma unroll
    for (int r = 0; r < 16; ++r) {
        __builtin_nontemporal_store(v4, o + threadIdx.x + 256 * r);
    }
}

extern "C" void kernel_launch(void* const* d_in, const int* in_sizes, int n_in,
                              void* d_out, int out_size, void* d_ws, size_t ws_size,
                              hipStream_t stream) {
    const float* x     = (const float*)d_in[0];
    const float* w_col = (const float*)d_in[1];
    const float* b_col = (const float*)d_in[2];
    const float* w_row = (const float*)d_in[3];
    const float* b_row = (const float*)d_in[4];
    float* out  = (float*)d_out;
    float* s_ws = (float*)d_ws;   // 4096 floats of scratch

    compute_s_kernel<<<256, 256, 0, stream>>>(x, w_col, b_col, w_row, b_row, s_ws);
    bcast_kernel<<<4096, 256, 0, stream>>>(s_ws, out);
}

// Round 4
// 76.529 us; speedup vs baseline: 1.0598x; 1.0598x over previous
//
#include <hip/hip_runtime.h>
#include <hip/hip_bf16.h>

// B=128, C=32, K=128
// out[b,c,i,j] = s[b,c],  s[b,c] = sum_k (u[c,k]+b_row[c]) * (v[c,k]+b_col[c])
//   u[c,k] = sum_i w_row[c,i] * X[b,i,k]   (column dot -> xt row read)
//   v[c,k] = sum_j w_col[c,j] * X[b,k,j]   (row dot    -> xt column read)

constexpr int KDIM = 128;
constexpr int CDIM = 32;

// XOR-swizzled word index into a [128][128] f32 LDS tile.
// 16B-chunk swizzle: chunk = (col>>2) ^ ((row>>2)&7). Conflict-free for:
//  - tile-transposed ds_write_b128 staging
//  - row-wise ds_read_b128 (u loop)
//  - column-wise ds_read_b32 (v loop)
__device__ __forceinline__ int swz_word(int row, int col) {
    return (row << 7) | ((((col >> 2) ^ ((row >> 2) & 7)) << 2) | (col & 3));
}

// grid = 256: blockIdx.x = b*2 + chalf ; block = 256 threads
__global__ __launch_bounds__(256) void compute_s_kernel(
    const float* __restrict__ x,
    const float* __restrict__ w_col, const float* __restrict__ b_col,
    const float* __restrict__ w_row, const float* __restrict__ b_row,
    float* __restrict__ s_out)
{
    __shared__ float xt[KDIM * KDIM];      // swizzled: xt[swz(k,i)] = X[i][k]  (64 KB)
    __shared__ float uv[2][16][KDIM];      // u and v results (16 KB)

    const int b   = blockIdx.x >> 1;
    const int ch  = blockIdx.x & 1;
    const int tid = threadIdx.x;

    // ---- stage X^T into swizzled LDS via 4x4 register tiles ----
    const float4* xsrc = reinterpret_cast<const float4*>(x + (size_t)b * KDIM * KDIM);
    const int tj  = tid & 31;    // column tile of X (row tile of xt)
    const int ti0 = tid >> 5;    // 0..7
    #pragma unroll
    for (int it = 0; it < 4; ++it) {
        const int ti = ti0 + 8 * it;                 // row tile of X, 0..31
        const float4 r0 = xsrc[(4 * ti + 0) * 32 + tj];   // coalesced
        const float4 r1 = xsrc[(4 * ti + 1) * 32 + tj];
        const float4 r2 = xsrc[(4 * ti + 2) * 32 + tj];
        const float4 r3 = xsrc[(4 * ti + 3) * 32 + tj];
        // xt row 4tj+t, cols 4ti..4ti+3  =  X[4ti..4ti+3][4tj+t]
        *reinterpret_cast<float4*>(&xt[swz_word(4 * tj + 0, 4 * ti)]) =
            make_float4(r0.x, r1.x, r2.x, r3.x);
        *reinterpret_cast<float4*>(&xt[swz_word(4 * tj + 1, 4 * ti)]) =
            make_float4(r0.y, r1.y, r2.y, r3.y);
        *reinterpret_cast<float4*>(&xt[swz_word(4 * tj + 2, 4 * ti)]) =
            make_float4(r0.z, r1.z, r2.z, r3.z);
        *reinterpret_cast<float4*>(&xt[swz_word(4 * tj + 3, 4 * ti)]) =
            make_float4(r0.w, r1.w, r2.w, r3.w);
    }
    __syncthreads();

    const int k   = tid & 127;
    const int sub = tid >> 7;    // wave-uniform: 0 -> u, 1 -> v

    float acc[16];
    #pragma unroll
    for (int c = 0; c < 16; ++c) acc[c] = 0.0f;

    if (sub == 0) {
        // u[c,k] = sum_i wr[c,i] * xt[k][i] — row read, ds_read_b128
        const float* wr = w_row + ch * 16 * KDIM;    // wave-uniform -> scalar loads
        #pragma unroll 4
        for (int iq = 0; iq < 32; ++iq) {
            const float4 xv = *reinterpret_cast<const float4*>(&xt[swz_word(k, iq << 2)]);
            #pragma unroll
            for (int c = 0; c < 16; ++c) {
                acc[c] = fmaf(wr[c * KDIM + 4 * iq + 0], xv.x, acc[c]);
                acc[c] = fmaf(wr[c * KDIM + 4 * iq + 1], xv.y, acc[c]);
                acc[c] = fmaf(wr[c * KDIM + 4 * iq + 2], xv.z, acc[c]);
                acc[c] = fmaf(wr[c * KDIM + 4 * iq + 3], xv.w, acc[c]);
            }
        }
    } else {
        // v[c,k] = sum_j wc[c,j] * xt[j][k] — column read, ds_read_b32 conflict-free
        const float* wc = w_col + ch * 16 * KDIM;    // wave-uniform -> scalar loads
        #pragma unroll 4
        for (int j = 0; j < KDIM; ++j) {
            const float xj = xt[swz_word(j, k)];
            #pragma unroll
            for (int c = 0; c < 16; ++c)
                acc[c] = fmaf(wc[c * KDIM + j], xj, acc[c]);
        }
    }
    #pragma unroll
    for (int c = 0; c < 16; ++c) uv[sub][c][k] = acc[c];
    __syncthreads();

    // ---- reduce over k: 16 groups of 16 lanes, group g owns c = ch*16 + g ----
    const int g    = tid >> 4;
    const int lane = tid & 15;
    const int cg   = ch * 16 + g;
    const float br = b_row[cg];
    const float bc = b_col[cg];

    float part = 0.0f;
    #pragma unroll
    for (int r = 0; r < 8; ++r) {
        const int kk = lane + 16 * r;
        part += (uv[0][g][kk] + br) * (uv[1][g][kk] + bc);
    }
    #pragma unroll
    for (int off = 8; off; off >>= 1)
        part += __shfl_xor(part, off, 16);

    if (lane == 0) s_out[b * CDIM + cg] = part;
}

// grid = 4096 (one block per (b,c) slab of 16384 floats), block = 256
// Plain float4 stores — nontemporal regressed (R3: L2 write-combining matters).
__global__ __launch_bounds__(256) void bcast_kernel(
    const float* __restrict__ s, float* __restrict__ out)
{
    const int bc = blockIdx.x;
    const float val = s[bc];
    float4 v4;
    v4.x = v4.y = v4.z = v4.w = val;
    float4* o = reinterpret_cast<float4*>(out) + (size_t)bc * 4096;
    #pragma unroll
    for (int r = 0; r < 16; ++r) {
        o[threadIdx.x + 256 * r] = v4;
    }
}

extern "C" void kernel_launch(void* const* d_in, const int* in_sizes, int n_in,
                              void* d_out, int out_size, void* d_ws, size_t ws_size,
                              hipStream_t stream) {
    const float* x     = (const float*)d_in[0];
    const float* w_col = (const float*)d_in[1];
    const float* b_col = (const float*)d_in[2];
    const float* w_row = (const float*)d_in[3];
    const float* b_row = (const float*)d_in[4];
    float* out  = (float*)d_out;
    float* s_ws = (float*)d_ws;   // 4096 floats of scratch

    compute_s_kernel<<<256, 256, 0, stream>>>(x, w_col, b_col, w_row, b_row, s_ws);
    bcast_kernel<<<4096, 256, 0, stream>>>(s_ws, out);
}

// Round 5
// 57.505 us; speedup vs baseline: 1.4104x; 1.3308x over previous
//
#include <hip/hip_runtime.h>
#include <hip/hip_bf16.h>

// B=128, C=32, K=128
// out[b,c,i,j] = s[b,c],  s[b,c] = sum_k (u[c,k]+b_row[c]) * (v[c,k]+b_col[c])
//   u[c,k] = sum_i w_row[c,i] * X[b,i,k]
//   v[c,k] = sum_j w_col[c,j] * X[b,k,j] = sum_j w_col[c,j] * XT[j,k]
//
// compute_s v2: 2c x 4k register tile. Inner iter = 1 ds_read_b128 (X, 4 k)
// + 1 ds_read_b64 (weight pair, 2-addr broadcast) -> 8 FMA. Cuts LDS-pipe
// cycles ~4-8x vs R1's 17 scalar reads / 16 FMA (LDS instr throughput is
// per-CU and was the 21-32us bottleneck).

constexpr int KDIM = 128;
constexpr int CDIM = 32;
constexpr int XS_LD = 132;   // padded row stride for xs (16B-aligned, breaks bank alignment)

// XOR chunk swizzle for the XT tile (linear [128][128]): conflict-free for
// 4x4-transpose b128 staging writes AND row-wise b128 reads (verified R4).
__device__ __forceinline__ int swz_word(int row, int col) {
    return (row << 7) | ((((col >> 2) ^ ((row >> 2) & 7)) << 2) | (col & 3));
}

// grid = 256: blockIdx.x = b*2 + ch ; block = 256 threads
__global__ __launch_bounds__(256) void compute_s_kernel(
    const float* __restrict__ x,
    const float* __restrict__ w_col, const float* __restrict__ b_col,
    const float* __restrict__ w_row, const float* __restrict__ b_row,
    float* __restrict__ s_out)
{
    __shared__ float  xs[KDIM * XS_LD];   // X row-major, padded   (66 KB)
    __shared__ float  xt[KDIM * KDIM];    // X^T, chunk-swizzled   (64 KB)
    __shared__ float2 wpr[KDIM][8];       // wpr[i][cg] = (w_row[C0+cg][i], w_row[C0+cg+8][i])  (8 KB)
    __shared__ float2 wpc[KDIM][8];       // same for w_col                                      (8 KB)

    const int b   = blockIdx.x >> 1;
    const int ch  = blockIdx.x & 1;
    const int tid = threadIdx.x;
    const int C0  = ch * 16;

    const float4* xsrc = reinterpret_cast<const float4*>(x + (size_t)b * KDIM * KDIM);

    // ---- stage X row-major (coalesced b128 copy) ----
    #pragma unroll
    for (int r = 0; r < 16; ++r) {
        const int idx4 = tid + 256 * r;          // 0..4095
        const int row  = idx4 >> 5;
        const int c4   = idx4 & 31;
        *reinterpret_cast<float4*>(&xs[row * XS_LD + 4 * c4]) = xsrc[idx4];
    }
    // ---- stage X^T via 4x4 register transpose into swizzled tile ----
    {
        const int tj  = tid & 31;
        const int ti0 = tid >> 5;
        #pragma unroll
        for (int it = 0; it < 4; ++it) {
            const int ti = ti0 + 8 * it;
            const float4 r0 = xsrc[(4 * ti + 0) * 32 + tj];
            const float4 r1 = xsrc[(4 * ti + 1) * 32 + tj];
            const float4 r2 = xsrc[(4 * ti + 2) * 32 + tj];
            const float4 r3 = xsrc[(4 * ti + 3) * 32 + tj];
            *reinterpret_cast<float4*>(&xt[swz_word(4 * tj + 0, 4 * ti)]) =
                make_float4(r0.x, r1.x, r2.x, r3.x);
            *reinterpret_cast<float4*>(&xt[swz_word(4 * tj + 1, 4 * ti)]) =
                make_float4(r0.y, r1.y, r2.y, r3.y);
            *reinterpret_cast<float4*>(&xt[swz_word(4 * tj + 2, 4 * ti)]) =
                make_float4(r0.z, r1.z, r2.z, r3.z);
            *reinterpret_cast<float4*>(&xt[swz_word(4 * tj + 3, 4 * ti)]) =
                make_float4(r0.w, r1.w, r2.w, r3.w);
        }
    }
    // ---- stage packed weight pairs: [128 i][8 cg] float2 ----
    #pragma unroll
    for (int e = 0; e < 4; ++e) {
        const int idx = tid + 256 * e;           // 0..1023
        const int i   = idx & 127;
        const int cg  = idx >> 7;                // 0..7
        wpr[i][cg] = make_float2(w_row[(C0 + cg) * KDIM + i],
                                 w_row[(C0 + cg + 8) * KDIM + i]);
        wpc[i][cg] = make_float2(w_col[(C0 + cg) * KDIM + i],
                                 w_col[(C0 + cg + 8) * KDIM + i]);
    }
    __syncthreads();

    const int kq = tid & 31;     // 4-k chunk index
    const int cg = tid >> 5;     // 0..7 ; this thread owns c0 = C0+cg, c1 = C0+cg+8

    float au0[4] = {0,0,0,0}, au1[4] = {0,0,0,0};
    float av0[4] = {0,0,0,0}, av1[4] = {0,0,0,0};

    // ---- u-pass: au[c][q] = sum_i wr[c][i] * X[i][4kq+q] ----
    #pragma unroll 4
    for (int i = 0; i < KDIM; ++i) {
        const float4 xv = *reinterpret_cast<const float4*>(&xs[i * XS_LD + 4 * kq]);
        const float2 w  = wpr[i][cg];
        au0[0] = fmaf(w.x, xv.x, au0[0]); au0[1] = fmaf(w.x, xv.y, au0[1]);
        au0[2] = fmaf(w.x, xv.z, au0[2]); au0[3] = fmaf(w.x, xv.w, au0[3]);
        au1[0] = fmaf(w.y, xv.x, au1[0]); au1[1] = fmaf(w.y, xv.y, au1[1]);
        au1[2] = fmaf(w.y, xv.z, au1[2]); au1[3] = fmaf(w.y, xv.w, au1[3]);
    }
    // ---- v-pass: av[c][q] = sum_j wc[c][j] * XT[j][4kq+q] ----
    #pragma unroll 4
    for (int j = 0; j < KDIM; ++j) {
        const float4 tv = *reinterpret_cast<const float4*>(&xt[swz_word(j, 4 * kq)]);
        const float2 w  = wpc[j][cg];
        av0[0] = fmaf(w.x, tv.x, av0[0]); av0[1] = fmaf(w.x, tv.y, av0[1]);
        av0[2] = fmaf(w.x, tv.z, av0[2]); av0[3] = fmaf(w.x, tv.w, av0[3]);
        av1[0] = fmaf(w.y, tv.x, av1[0]); av1[1] = fmaf(w.y, tv.y, av1[1]);
        av1[2] = fmaf(w.y, tv.z, av1[2]); av1[3] = fmaf(w.y, tv.w, av1[3]);
    }

    // ---- dot + bias, then reduce over the 32 kq lanes ----
    const int c0 = C0 + cg, c1 = C0 + cg + 8;
    const float br0 = b_row[c0], bc0 = b_col[c0];
    const float br1 = b_row[c1], bc1 = b_col[c1];

    float p0 = 0.f, p1 = 0.f;
    #pragma unroll
    for (int q = 0; q < 4; ++q) {
        p0 += (au0[q] + br0) * (av0[q] + bc0);
        p1 += (au1[q] + br1) * (av1[q] + bc1);
    }
    #pragma unroll
    for (int off = 16; off; off >>= 1) {
        p0 += __shfl_xor(p0, off, 32);
        p1 += __shfl_xor(p1, off, 32);
    }
    if (kq == 0) {
        s_out[b * CDIM + c0] = p0;
        s_out[b * CDIM + c1] = p1;
    }
}

// grid = 4096 (one block per (b,c) slab of 16384 floats), block = 256
// Plain float4 stores — nontemporal regressed (R3).
__global__ __launch_bounds__(256) void bcast_kernel(
    const float* __restrict__ s, float* __restrict__ out)
{
    const int bc = blockIdx.x;
    const float val = s[bc];
    float4 v4;
    v4.x = v4.y = v4.z = v4.w = val;
    float4* o = reinterpret_cast<float4*>(out) + (size_t)bc * 4096;
    #pragma unroll
    for (int r = 0; r < 16; ++r) {
        o[threadIdx.x + 256 * r] = v4;
    }
}

extern "C" void kernel_launch(void* const* d_in, const int* in_sizes, int n_in,
                              void* d_out, int out_size, void* d_ws, size_t ws_size,
                              hipStream_t stream) {
    const float* x     = (const float*)d_in[0];
    const float* w_col = (const float*)d_in[1];
    const float* b_col = (const float*)d_in[2];
    const float* w_row = (const float*)d_in[3];
    const float* b_row = (const float*)d_in[4];
    float* out  = (float*)d_out;
    float* s_ws = (float*)d_ws;   // 4096 floats of scratch

    compute_s_kernel<<<256, 256, 0, stream>>>(x, w_col, b_col, w_row, b_row, s_ws);
    bcast_kernel<<<4096, 256, 0, stream>>>(s_ws, out);
}